// Round 11
// baseline (12032.736 us; speedup 1.0000x reference)
//
#include <hip/hip_runtime.h>

namespace {
constexpr int E_ = 512;
constexpr int H_ = 512;
constexpr int O_ = 32;
constexpr int B_ = 64;
constexpr int T_ = 512;
constexpr int RING = 8;
constexpr int FPAD = 16;                               // 64B per flag
// ws layout (floats)
constexpr size_t H0_OFF   = 0;                         // RING*B*H = 262144
constexpr size_t H1_OFF   = (size_t)RING * B_ * H_;    // 262144
constexpr size_t HF_OFF   = 2 * H1_OFF;                // 524288
constexpr size_t FLAG_OFF = HF_OFF + (size_t)B_ * H_;  // 557056
constexpr size_t FLAG_UINTS = 2u * 8u * 32u * FPAD;    // 8192
constexpr size_t WS_REQUIRED = (FLAG_OFF + FLAG_UINTS) * 4;
}

typedef float f32x4 __attribute__((ext_vector_type(4)));

// ---- coherent LLC primitives; ALL self-contained (waitcnt inside asm).
// 13-bit signed imm offsets: one base VGPR pair per 4KB window. ----
// 4 elems x 2 k-chunks of one ring vector set (elem stride 2048B).
__device__ __forceinline__ void ring_load8(const float* p, f32x4 H[8]) {
    const float* p2 = p + 1024;   // +4096 B
    asm volatile(
        "global_load_dwordx4 %0, %8, off sc0 sc1\n\t"
        "global_load_dwordx4 %1, %8, off offset:1024 sc0 sc1\n\t"
        "global_load_dwordx4 %2, %8, off offset:2048 sc0 sc1\n\t"
        "global_load_dwordx4 %3, %8, off offset:3072 sc0 sc1\n\t"
        "global_load_dwordx4 %4, %9, off sc0 sc1\n\t"
        "global_load_dwordx4 %5, %9, off offset:1024 sc0 sc1\n\t"
        "global_load_dwordx4 %6, %9, off offset:2048 sc0 sc1\n\t"
        "global_load_dwordx4 %7, %9, off offset:3072 sc0 sc1\n\t"
        "s_waitcnt vmcnt(0)"
        : "=&v"(H[0]), "=&v"(H[1]), "=&v"(H[2]), "=&v"(H[3]),
          "=&v"(H[4]), "=&v"(H[5]), "=&v"(H[6]), "=&v"(H[7])
        : "v"(p), "v"(p2) : "memory");
}
// both vector sets in ONE round trip (L1 non-lookahead path)
__device__ __forceinline__ void ring_load16(const float* p0, const float* p1,
                                            f32x4 A[8], f32x4 Bv[8]) {
    const float* p0b = p0 + 1024;
    const float* p1b = p1 + 1024;
    asm volatile(
        "global_load_dwordx4 %0, %16, off sc0 sc1\n\t"
        "global_load_dwordx4 %1, %16, off offset:1024 sc0 sc1\n\t"
        "global_load_dwordx4 %2, %16, off offset:2048 sc0 sc1\n\t"
        "global_load_dwordx4 %3, %16, off offset:3072 sc0 sc1\n\t"
        "global_load_dwordx4 %4, %17, off sc0 sc1\n\t"
        "global_load_dwordx4 %5, %17, off offset:1024 sc0 sc1\n\t"
        "global_load_dwordx4 %6, %17, off offset:2048 sc0 sc1\n\t"
        "global_load_dwordx4 %7, %17, off offset:3072 sc0 sc1\n\t"
        "global_load_dwordx4 %8, %18, off sc0 sc1\n\t"
        "global_load_dwordx4 %9, %18, off offset:1024 sc0 sc1\n\t"
        "global_load_dwordx4 %10, %18, off offset:2048 sc0 sc1\n\t"
        "global_load_dwordx4 %11, %18, off offset:3072 sc0 sc1\n\t"
        "global_load_dwordx4 %12, %19, off sc0 sc1\n\t"
        "global_load_dwordx4 %13, %19, off offset:1024 sc0 sc1\n\t"
        "global_load_dwordx4 %14, %19, off offset:2048 sc0 sc1\n\t"
        "global_load_dwordx4 %15, %19, off offset:3072 sc0 sc1\n\t"
        "s_waitcnt vmcnt(0)"
        : "=&v"(A[0]), "=&v"(A[1]), "=&v"(A[2]), "=&v"(A[3]),
          "=&v"(A[4]), "=&v"(A[5]), "=&v"(A[6]), "=&v"(A[7]),
          "=&v"(Bv[0]), "=&v"(Bv[1]), "=&v"(Bv[2]), "=&v"(Bv[3]),
          "=&v"(Bv[4]), "=&v"(Bv[5]), "=&v"(Bv[6]), "=&v"(Bv[7])
        : "v"(p0), "v"(p0b), "v"(p1), "v"(p1b) : "memory");
}
__device__ __forceinline__ unsigned flag_poll(const unsigned* p) {
    unsigned v;
    asm volatile("global_load_dword %0, %1, off sc0 sc1\n\ts_waitcnt vmcnt(0)"
                 : "=&v"(v) : "v"(p) : "memory");
    return v;
}
__device__ __forceinline__ void vm_drain() {
    asm volatile("s_waitcnt vmcnt(0)" ::: "memory");
}
__device__ __forceinline__ void coh_store(float* p, float v) {
    asm volatile("global_store_dword %0, %1, off sc0 sc1" :: "v"(p), "v"(v) : "memory");
}
__device__ __forceinline__ void flag_store(unsigned* p, unsigned v) {
    asm volatile("global_store_dword %0, %1, off sc0 sc1" :: "v"(p), "v"(v) : "memory");
}

__device__ __forceinline__ float fast_tanh(float x) {
    float e = __builtin_amdgcn_exp2f(x * 2.885390081777927f);
    return 1.0f - 2.0f * __builtin_amdgcn_rcpf(e + 1.0f);
}

// pair-combine butterfly: v[4] partials/lane -> full sum of row (lane&3) on every lane
__device__ __forceinline__ float reduce4(const float v[4], int lane) {
    float a[2];
#pragma unroll
    for (int j = 0; j < 2; ++j) {
        const int sel = lane & 1;
        const float mine = sel ? v[2 * j + 1] : v[2 * j];
        const float send = sel ? v[2 * j] : v[2 * j + 1];
        a[j] = mine + __shfl_xor(send, 1, 64);
    }
    const int sel = (lane >> 1) & 1;
    const float mine = sel ? a[1] : a[0];
    const float send = sel ? a[0] : a[1];
    float s = mine + __shfl_xor(send, 2, 64);
    s += __shfl_xor(s, 4, 64);
    s += __shfl_xor(s, 8, 64);
    s += __shfl_xor(s, 16, 64);
    s += __shfl_xor(s, 32, 64);
    return s;
}

// =====================================================================
// 512 blocks = 2 layers x 8 groups(8 elems) x 32 chunks(16 rows); 8 waves;
// wave = 4 rows (wr=wid&3) x 4 elems (we=wid>>2); bounds(512,4) -> 2 blk/CU.
// Per-step critical path (vs r9): 2 barriers (was 3), h operands loaded
// straight to registers in ONE self-contained LLC round trip (was LDS
// stage = +1 barrier +1 RT), wave0 polls BEFORE phase A so the poll RT
// overlaps other waves' emb-half FMAs, and L1 pre-computes the x-half
// using last step's lookahead observation (cnt0 >= t+2 recorded in LDS).
// =====================================================================
__global__ __launch_bounds__(512, 4) void rnn_pipe9(
    const int* __restrict__ x, const int* __restrict__ seq_lens,
    const float* __restrict__ emb,
    const float* __restrict__ Whx, const float* __restrict__ Whh,
    const float* __restrict__ b_h,
    float* __restrict__ h0_ring, float* __restrict__ h1_ring,
    float* __restrict__ h1_final, unsigned* __restrict__ flags)
{
    const int bid   = blockIdx.x;
    const int layer = bid >> 8;          // 0..1
    const int g     = (bid >> 5) & 7;    // group of 8 elems
    const int c     = bid & 31;          // chunk of 16 rows
    const int tid   = threadIdx.x;
    const int wid   = tid >> 6;
    const int lane  = tid & 63;
    const int we    = wid >> 2;          // elem quad (0..1)
    const int wr    = wid & 3;           // row quad (0..3)
    const int rowbase = c * 16 + wr * 4;
    const int eg0   = g * 8 + we * 4;

    __shared__ float sx[2][4096];        // L0 emb double-buffer
    __shared__ unsigned s_la[2];         // L1 lookahead flags

    const float* WxL = Whx + (size_t)layer * H_ * E_;
    const float* WhL = Whh + (size_t)layer * H_ * H_;
    f32x4 wx0[4], wx1[4], wh0[4], wh1[4];
#pragma unroll
    for (int r = 0; r < 4; ++r) {
        const int row = rowbase + r;
        wx0[r] = *(const f32x4*)(WxL + (size_t)row * E_ + (lane << 2));
        wx1[r] = *(const f32x4*)(WxL + (size_t)row * E_ + 256 + (lane << 2));
        wh0[r] = *(const f32x4*)(WhL + (size_t)row * H_ + (lane << 2));
        wh1[r] = *(const f32x4*)(WhL + (size_t)row * H_ + 256 + (lane << 2));
    }
    const float bias = b_h[layer * H_ + rowbase + (lane & 3)];

    int sl4[4];
#pragma unroll
    for (int q = 0; q < 4; ++q) sl4[q] = seq_lens[eg0 + q];
    int Tg = 1;
#pragma unroll
    for (int j = 0; j < 8; ++j) {
        const int s = seq_lens[g * 8 + j];
        Tg = s > Tg ? s : Tg;
    }

    // flags: [2][8][32] x FPAD. Wave0: lanes 0..31 watch L0 set, 32..63 L1 set.
    unsigned* const myflag = flags + ((size_t)((layer * 8 + g) * 32 + c)) * FPAD;
    const unsigned* const pollp = (lane < 32)
        ? flags + ((size_t)(g * 32 + lane)) * FPAD
        : flags + ((size_t)((8 + g) * 32 + (lane - 32))) * FPAD;

    const int se  = wid;
    const int seg = g * 8 + se;

    long budget = 1l << 24;

    if (layer == 0) {
        // prologue: stage x(0) at 16B lane stride (conflict-free)
        {
            const int tok = x[(size_t)seg * T_];
            *(f32x4*)&sx[0][(se << 9) + (lane << 2)] =
                *(const f32x4*)(emb + ((size_t)tok << 9) + (lane << 2));
            *(f32x4*)&sx[0][(se << 9) + 256 + (lane << 2)] =
                *(const f32x4*)(emb + ((size_t)tok << 9) + 256 + (lane << 2));
        }
        __syncthreads();

        for (int t = 0; t < Tg; ++t) {
            const int cur = t & 1, slot = t & 7, pslot = (t - 1) & 7;
            float vvp[4][4];

            // ---- wave0 polls FIRST (overlaps other waves' phase A) ----
            if (wid == 0 && t > 0) {
                const int tgt = (lane < 32) ? t : t - 7;   // cnt0>=t; cnt1>=t-7
                for (;;) {
                    const unsigned v = flag_poll(pollp);
                    if (!__any((int)v < tgt)) break;
                    if (--budget < 0) break;
                }
            }

            // ---- phase A: emb-half (all waves) ----
#pragma unroll
            for (int q = 0; q < 4; ++q) {
                if (t >= sl4[q]) continue;
                const int el = (we << 2) + q;
                const f32x4 lx0 = *(const f32x4*)&sx[cur][(el << 9) + (lane << 2)];
                const f32x4 lx1 = *(const f32x4*)&sx[cur][(el << 9) + 256 + (lane << 2)];
#pragma unroll
                for (int r = 0; r < 4; ++r) {
                    float s = wx0[r][0] * lx0[0];
                    s = fmaf(wx0[r][1], lx0[1], s);
                    s = fmaf(wx0[r][2], lx0[2], s);
                    s = fmaf(wx0[r][3], lx0[3], s);
                    s = fmaf(wx1[r][0], lx1[0], s);
                    s = fmaf(wx1[r][1], lx1[1], s);
                    s = fmaf(wx1[r][2], lx1[2], s);
                    s = fmaf(wx1[r][3], lx1[3], s);
                    vvp[q][r] = s;
                }
            }
            f32x4 px0, px1;
            const bool havepf = (t + 1 < Tg);
            if (havepf) {
                const int tok = x[(size_t)seg * T_ + t + 1];
                px0 = *(const f32x4*)(emb + ((size_t)tok << 9) + (lane << 2));
                px1 = *(const f32x4*)(emb + ((size_t)tok << 9) + 256 + (lane << 2));
            }
            __syncthreads();                       // barrier 1 (gates ring reads)

            // ---- phase B: reg-load h0(t-1), h-half, epilogue ----
            f32x4 H[8];
            if (t > 0) {
                ring_load8(h0_ring + (((size_t)pslot << 6) + eg0) * 512 + (lane << 2), H);
            } else {
#pragma unroll
                for (int i = 0; i < 8; ++i) H[i] = 0;
            }
#pragma unroll
            for (int q = 0; q < 4; ++q) {
                if (t >= sl4[q]) continue;
#pragma unroll
                for (int r = 0; r < 4; ++r) {
                    float s = vvp[q][r];
                    s = fmaf(wh0[r][0], H[2 * q][0], s);
                    s = fmaf(wh0[r][1], H[2 * q][1], s);
                    s = fmaf(wh0[r][2], H[2 * q][2], s);
                    s = fmaf(wh0[r][3], H[2 * q][3], s);
                    s = fmaf(wh1[r][0], H[2 * q + 1][0], s);
                    s = fmaf(wh1[r][1], H[2 * q + 1][1], s);
                    s = fmaf(wh1[r][2], H[2 * q + 1][2], s);
                    s = fmaf(wh1[r][3], H[2 * q + 1][3], s);
                    vvp[q][r] = s;
                }
                const float sum = reduce4(vvp[q], lane);
                const float hv = fast_tanh(sum + bias);
                if (lane < 4)
                    coh_store(h0_ring + (((size_t)slot << 6) + eg0 + q) * 512 + rowbase + lane, hv);
            }
            if (havepf) {
                *(f32x4*)&sx[cur ^ 1][(se << 9) + (lane << 2)] = px0;
                *(f32x4*)&sx[cur ^ 1][(se << 9) + 256 + (lane << 2)] = px1;
            }
            vm_drain();
            __syncthreads();                       // barrier 2
            if (tid == 0) flag_store(myflag, (unsigned)(t + 1));
        }
    } else {
        // ---- layer 1 ----
        if (tid == 0) { s_la[0] = 0; s_la[1] = 0; }
        __syncthreads();

        for (int t = 0; t < Tg; ++t) {
            const int slot = t & 7, pslot = (t - 1) & 7;
            float vvp[4][4];
            f32x4 Hx[8];
            bool have_x = false;

            // ---- lookahead x-half: h0(t) known-committed from last step's poll ----
            const bool la = (t > 0) && (s_la[t & 1] != 0u);
            if (la) {
                ring_load8(h0_ring + (((size_t)slot << 6) + eg0) * 512 + (lane << 2), Hx);
#pragma unroll
                for (int q = 0; q < 4; ++q) {
                    if (t >= sl4[q]) continue;
#pragma unroll
                    for (int r = 0; r < 4; ++r) {
                        float s = wx0[r][0] * Hx[2 * q][0];
                        s = fmaf(wx0[r][1], Hx[2 * q][1], s);
                        s = fmaf(wx0[r][2], Hx[2 * q][2], s);
                        s = fmaf(wx0[r][3], Hx[2 * q][3], s);
                        s = fmaf(wx1[r][0], Hx[2 * q + 1][0], s);
                        s = fmaf(wx1[r][1], Hx[2 * q + 1][1], s);
                        s = fmaf(wx1[r][2], Hx[2 * q + 1][2], s);
                        s = fmaf(wx1[r][3], Hx[2 * q + 1][3], s);
                        vvp[q][r] = s;
                    }
                }
                have_x = true;
            }
            // ---- wave0 poll (+ record lookahead for t+1) ----
            if (wid == 0) {
                const int tgt = (lane < 32) ? t + 1 : t;   // cnt0>=t+1; cnt1>=t
                unsigned v = 0;
                for (;;) {
                    v = flag_poll(pollp);
                    if (!__any((int)v < tgt)) break;
                    if (--budget < 0) break;
                }
                const bool la_next = !__any((lane < 32) && ((int)v < t + 2));
                if (lane == 0) s_la[(t + 1) & 1] = la_next ? 1u : 0u;
            }
            __syncthreads();                       // barrier 1

            // ---- gated loads + remaining FMAs ----
            f32x4 H1[8];
            if (!have_x) {
                if (t > 0) {
                    ring_load16(h0_ring + (((size_t)slot << 6) + eg0) * 512 + (lane << 2),
                                h1_ring + (((size_t)pslot << 6) + eg0) * 512 + (lane << 2),
                                Hx, H1);
                } else {
                    ring_load8(h0_ring + (((size_t)slot << 6) + eg0) * 512 + (lane << 2), Hx);
                }
#pragma unroll
                for (int q = 0; q < 4; ++q) {
                    if (t >= sl4[q]) continue;
#pragma unroll
                    for (int r = 0; r < 4; ++r) {
                        float s = wx0[r][0] * Hx[2 * q][0];
                        s = fmaf(wx0[r][1], Hx[2 * q][1], s);
                        s = fmaf(wx0[r][2], Hx[2 * q][2], s);
                        s = fmaf(wx0[r][3], Hx[2 * q][3], s);
                        s = fmaf(wx1[r][0], Hx[2 * q + 1][0], s);
                        s = fmaf(wx1[r][1], Hx[2 * q + 1][1], s);
                        s = fmaf(wx1[r][2], Hx[2 * q + 1][2], s);
                        s = fmaf(wx1[r][3], Hx[2 * q + 1][3], s);
                        vvp[q][r] = s;
                    }
                }
            } else if (t > 0) {
                ring_load8(h1_ring + (((size_t)pslot << 6) + eg0) * 512 + (lane << 2), H1);
            }

            if (t > 0) {
#pragma unroll
                for (int q = 0; q < 4; ++q) {
                    if (t >= sl4[q]) continue;
#pragma unroll
                    for (int r = 0; r < 4; ++r) {
                        float s = vvp[q][r];
                        s = fmaf(wh0[r][0], H1[2 * q][0], s);
                        s = fmaf(wh0[r][1], H1[2 * q][1], s);
                        s = fmaf(wh0[r][2], H1[2 * q][2], s);
                        s = fmaf(wh0[r][3], H1[2 * q][3], s);
                        s = fmaf(wh1[r][0], H1[2 * q + 1][0], s);
                        s = fmaf(wh1[r][1], H1[2 * q + 1][1], s);
                        s = fmaf(wh1[r][2], H1[2 * q + 1][2], s);
                        s = fmaf(wh1[r][3], H1[2 * q + 1][3], s);
                        vvp[q][r] = s;
                    }
                }
            }
#pragma unroll
            for (int q = 0; q < 4; ++q) {
                if (t >= sl4[q]) continue;
                const float sum = reduce4(vvp[q], lane);
                const float hv = fast_tanh(sum + bias);
                if (lane < 4) {
                    coh_store(h1_ring + (((size_t)slot << 6) + eg0 + q) * 512 + rowbase + lane, hv);
                    if (t == sl4[q] - 1)
                        h1_final[((size_t)(eg0 + q) << 9) + rowbase + lane] = hv;
                }
            }
            vm_drain();
            __syncthreads();                       // barrier 2
            if (tid == 0) flag_store(myflag, (unsigned)(t + 1));
        }
    }
}

// ---- final head: y = Wyh[1] @ h1 + b_y[1]; out = Wf @ y + bf ----
__device__ __forceinline__ float dot4(float4 a, float4 b) {
    return fmaf(a.x, b.x, fmaf(a.y, b.y, fmaf(a.z, b.z, a.w * b.w)));
}
__device__ __forceinline__ float wave_reduce(float acc) {
#pragma unroll
    for (int off = 32; off > 0; off >>= 1) acc += __shfl_down(acc, off, 64);
    return acc;
}

__global__ __launch_bounds__(512) void head_kernel(
    const float* __restrict__ h1f, const float* __restrict__ Wyh,
    const float* __restrict__ b_y, const float* __restrict__ Wf,
    const float* __restrict__ bf, float* __restrict__ out)
{
    const int e = blockIdx.x;
    const int tid = threadIdx.x, wid = tid >> 6, lane = tid & 63;
    const int k0 = lane << 3;
    __shared__ float sh[H_];
    __shared__ float sy[H_];
    sh[tid] = h1f[(size_t)e * H_ + tid];
    __syncthreads();
    const float4 hA = *(const float4*)&sh[k0];
    const float4 hB = *(const float4*)&sh[k0 + 4];
    const float* Wy1 = Wyh + H_ * H_;
#pragma unroll 4
    for (int rr = 0; rr < 64; ++rr) {
        const int row = (wid << 6) + rr;
        float acc = wave_reduce(dot4(*(const float4*)&Wy1[(size_t)row * H_ + k0], hA) +
                                dot4(*(const float4*)&Wy1[(size_t)row * H_ + k0 + 4], hB));
        if (lane == 0) sy[row] = acc + b_y[H_ + row];
    }
    __syncthreads();
    const float4 yA = *(const float4*)&sy[k0];
    const float4 yB = *(const float4*)&sy[k0 + 4];
#pragma unroll
    for (int rr = 0; rr < 4; ++rr) {
        const int o = (wid << 2) + rr;
        float acc = wave_reduce(dot4(*(const float4*)&Wf[(size_t)o * H_ + k0], yA) +
                                dot4(*(const float4*)&Wf[(size_t)o * H_ + k0 + 4], yB));
        if (lane == 0) out[(size_t)e * O_ + o] = acc + bf[o];
    }
}

// ---- fallback (round-0, known-passing) ----
__global__ __launch_bounds__(1024, 1) void rnn_fused_fb(
    const int* __restrict__ x, const int* __restrict__ seq_lens,
    const float* __restrict__ emb, const float* __restrict__ Whx,
    const float* __restrict__ Whh, const float* __restrict__ b_h,
    const float* __restrict__ Wyh, const float* __restrict__ b_y,
    const float* __restrict__ Wf, const float* __restrict__ bf,
    float* __restrict__ out)
{
    const int b = blockIdx.x, tid = threadIdx.x;
    const int wave = tid >> 6, lane = tid & 63, k0 = lane << 3;
    __shared__ float s_inp[E_];
    __shared__ float s_h0[2][H_];
    __shared__ float s_h1[2][H_];
    __shared__ float s_y[H_];
    if (tid < H_) { s_h0[0][tid]=0.f; s_h0[1][tid]=0.f; s_h1[0][tid]=0.f; s_h1[1][tid]=0.f; }
    const int Tb = seq_lens[b];
    const float* Whx0 = Whx; const float* Whx1 = Whx + H_*E_;
    const float* Whh0 = Whh; const float* Whh1 = Whh + H_*H_;
    for (int t = 0; t < Tb; ++t) {
        const int cur = t & 1, prv = cur ^ 1;
        if (tid < E_) { const int tok = x[b*T_+t]; s_inp[tid] = emb[(size_t)tok*E_+tid]; }
        __syncthreads();
        const float4 iA = *(const float4*)&s_inp[k0], iB = *(const float4*)&s_inp[k0+4];
        const float4 pA = *(const float4*)&s_h0[prv][k0], pB = *(const float4*)&s_h0[prv][k0+4];
#pragma unroll 4
        for (int r = 0; r < 32; ++r) {
            const int i = (wave<<5)+r;
            float acc = dot4(*(const float4*)&Whx0[i*E_+k0], iA) + dot4(*(const float4*)&Whx0[i*E_+k0+4], iB)
                      + dot4(*(const float4*)&Whh0[i*H_+k0], pA) + dot4(*(const float4*)&Whh0[i*H_+k0+4], pB);
            acc = wave_reduce(acc);
            if (lane == 0) s_h0[cur][i] = tanhf(acc + b_h[i]);
        }
        __syncthreads();
        const float4 cA = *(const float4*)&s_h0[cur][k0], cB = *(const float4*)&s_h0[cur][k0+4];
        const float4 qA = *(const float4*)&s_h1[prv][k0], qB = *(const float4*)&s_h1[prv][k0+4];
#pragma unroll 4
        for (int r = 0; r < 32; ++r) {
            const int i = (wave<<5)+r;
            float acc = dot4(*(const float4*)&Whx1[i*E_+k0], cA) + dot4(*(const float4*)&Whx1[i*E_+k0+4], cB)
                      + dot4(*(const float4*)&Whh1[i*H_+k0], qA) + dot4(*(const float4*)&Whh1[i*H_+k0+4], qB);
            acc = wave_reduce(acc);
            if (lane == 0) s_h1[cur][i] = tanhf(acc + b_h[H_+i]);
        }
        __syncthreads();
    }
    const int lastb = (Tb-1) & 1;
    const float4 hA = *(const float4*)&s_h1[lastb][k0], hB = *(const float4*)&s_h1[lastb][k0+4];
    const float* Wy1 = Wyh + H_*H_;
#pragma unroll 4
    for (int r = 0; r < 32; ++r) {
        const int i = (wave<<5)+r;
        float acc = wave_reduce(dot4(*(const float4*)&Wy1[i*H_+k0], hA) + dot4(*(const float4*)&Wy1[i*H_+k0+4], hB));
        if (lane == 0) s_y[i] = acc + b_y[H_+i];
    }
    __syncthreads();
    const float4 yA = *(const float4*)&s_y[k0], yB = *(const float4*)&s_y[k0+4];
    if (wave < 8) {
#pragma unroll
        for (int r = 0; r < 4; ++r) {
            const int o = (wave<<2)+r;
            float acc = wave_reduce(dot4(*(const float4*)&Wf[o*H_+k0], yA) + dot4(*(const float4*)&Wf[o*H_+k0+4], yB));
            if (lane == 0) out[b*O_+o] = acc + bf[o];
        }
    }
}

extern "C" void kernel_launch(void* const* d_in, const int* in_sizes, int n_in,
                              void* d_out, int out_size, void* d_ws, size_t ws_size,
                              hipStream_t stream) {
    const int*   x    = (const int*)d_in[0];
    const int*   sl   = (const int*)d_in[1];
    const float* emb  = (const float*)d_in[2];
    const float* Whx  = (const float*)d_in[3];
    const float* Whh  = (const float*)d_in[4];
    const float* b_h  = (const float*)d_in[5];
    const float* Wyh  = (const float*)d_in[6];
    const float* b_y  = (const float*)d_in[7];
    const float* Wf   = (const float*)d_in[8];
    const float* bf   = (const float*)d_in[9];
    float* out = (float*)d_out;

    if (ws_size < WS_REQUIRED) {
        rnn_fused_fb<<<B_, 1024, 0, stream>>>(x, sl, emb, Whx, Whh, b_h, Wyh, b_y, Wf, bf, out);
        return;
    }

    float* ws_f = (float*)d_ws;
    float* h0_ring = ws_f + H0_OFF;
    float* h1_ring = ws_f + H1_OFF;
    float* h1f     = ws_f + HF_OFF;
    unsigned* flags = (unsigned*)(ws_f + FLAG_OFF);

    hipMemsetAsync(flags, 0, FLAG_UINTS * sizeof(unsigned), stream);
    rnn_pipe9<<<512, 512, 0, stream>>>(x, sl, emb, Whx, Whh, b_h,
                                       h0_ring, h1_ring, h1f, flags);
    head_kernel<<<B_, 512, 0, stream>>>(h1f, Wyh, b_y, Wf, bf, out);
}

// Round 12
// 1938.624 us; speedup vs baseline: 6.2068x; 6.2068x over previous
//
#include <hip/hip_runtime.h>

namespace {
constexpr int E_ = 512;
constexpr int H_ = 512;
constexpr int O_ = 32;
constexpr int B_ = 64;
constexpr int T_ = 512;
constexpr int RING = 8;
constexpr int FPAD = 16;                               // 64B per flag
// ws layout (floats)
constexpr size_t H0_OFF   = 0;                         // RING*B*H = 262144
constexpr size_t H1_OFF   = (size_t)RING * B_ * H_;    // 262144
constexpr size_t HF_OFF   = 2 * H1_OFF;                // 524288
constexpr size_t FLAG_OFF = HF_OFF + (size_t)B_ * H_;  // 557056
constexpr size_t FLAG_UINTS = 8u * 32u * FPAD;         // 4096 (L1 consume-flags only)
constexpr size_t WS_REQUIRED = (FLAG_OFF + FLAG_UINTS) * 4;
}

typedef float f32x4 __attribute__((ext_vector_type(4)));

// ---- coherent LLC primitives; self-contained (waitcnt inside asm) ----
__device__ __forceinline__ void coh_ld2k(const float* p, f32x4& a, f32x4& b) {
    asm volatile(
        "global_load_dwordx4 %0, %2, off sc0 sc1\n\t"
        "global_load_dwordx4 %1, %2, off offset:1024 sc0 sc1\n\t"
        "s_waitcnt vmcnt(0)"
        : "=&v"(a), "=&v"(b) : "v"(p) : "memory");
}
__device__ __forceinline__ void coh_ld4k(const float* p, const float* q,
                                         f32x4& a, f32x4& b, f32x4& c, f32x4& d) {
    asm volatile(
        "global_load_dwordx4 %0, %4, off sc0 sc1\n\t"
        "global_load_dwordx4 %1, %4, off offset:1024 sc0 sc1\n\t"
        "global_load_dwordx4 %2, %5, off sc0 sc1\n\t"
        "global_load_dwordx4 %3, %5, off offset:1024 sc0 sc1\n\t"
        "s_waitcnt vmcnt(0)"
        : "=&v"(a), "=&v"(b), "=&v"(c), "=&v"(d) : "v"(p), "v"(q) : "memory");
}
__device__ __forceinline__ unsigned flag_poll(const unsigned* p) {
    unsigned v;
    asm volatile("global_load_dword %0, %1, off sc0 sc1\n\ts_waitcnt vmcnt(0)"
                 : "=&v"(v) : "v"(p) : "memory");
    return v;
}
__device__ __forceinline__ void coh_store_u(float* p, unsigned v) {
    asm volatile("global_store_dword %0, %1, off sc0 sc1" :: "v"(p), "v"(v) : "memory");
}
__device__ __forceinline__ void flag_store(unsigned* p, unsigned v) {
    asm volatile("global_store_dword %0, %1, off sc0 sc1" :: "v"(p), "v"(v) : "memory");
}

__device__ __forceinline__ float fast_tanh(float x) {
    float e = __builtin_amdgcn_exp2f(x * 2.885390081777927f);
    return 1.0f - 2.0f * __builtin_amdgcn_rcpf(e + 1.0f);
}

// pair-combine butterfly: v[4] partials/lane -> full sum of row (lane&3) on every lane
__device__ __forceinline__ float reduce4(const float v[4], int lane) {
    float a[2];
#pragma unroll
    for (int j = 0; j < 2; ++j) {
        const int sel = lane & 1;
        const float mine = sel ? v[2 * j + 1] : v[2 * j];
        const float send = sel ? v[2 * j] : v[2 * j + 1];
        a[j] = mine + __shfl_xor(send, 1, 64);
    }
    const int sel = (lane >> 1) & 1;
    const float mine = sel ? a[1] : a[0];
    const float send = sel ? a[0] : a[1];
    float s = mine + __shfl_xor(send, 2, 64);
    s += __shfl_xor(s, 4, 64);
    s += __shfl_xor(s, 8, 64);
    s += __shfl_xor(s, 16, 64);
    s += __shfl_xor(s, 32, 64);
    return s;
}

// =====================================================================
// 512 blocks = 2 layers x 8 groups(8 elems) x 32 chunks(16 rows); 8 waves;
// wave = 4 rows x 4 elems; bounds(512,4) -> 2 blocks/CU; LDS dedup staging
// (r10 lesson: per-wave coherent reg loads = 128x redundancy = 19GB HBM).
// DATA-VALIDITY handshake: h stored as bits(h) XOR epoch-mask, where
// epoch=(t>>3)&1. |tanh|<=1 -> exponent<=127 -> bit30 of the stored word
// equals the epoch. Stager loads, XOR-decodes (which doubles as the
// freshness check: OR all words, test bit30), retries until fresh.
// This merges poll+stage into ONE LLC RT, removes vm_drain and L0 flag
// stores from the critical path. L1 posts consume-flags only (ring
// backpressure for L0, 8-step slack, off critical path).
// =====================================================================
__global__ __launch_bounds__(512, 4) void rnn_pipe11(
    const int* __restrict__ x, const int* __restrict__ seq_lens,
    const float* __restrict__ emb,
    const float* __restrict__ Whx, const float* __restrict__ Whh,
    const float* __restrict__ b_h,
    float* __restrict__ h0_ring, float* __restrict__ h1_ring,
    float* __restrict__ h1_final, unsigned* __restrict__ flags)
{
    const int bid   = blockIdx.x;
    const int layer = bid >> 8;          // 0..1
    const int g     = (bid >> 5) & 7;    // group of 8 elems
    const int c     = bid & 31;          // chunk of 16 rows
    const int tid   = threadIdx.x;
    const int wid   = tid >> 6;
    const int lane  = tid & 63;
    const int we    = wid >> 2;          // elem quad (0..1)
    const int wr    = wid & 3;           // row quad (0..3)
    const int rowbase = c * 16 + wr * 4;
    const int eg0   = g * 8 + we * 4;

    // smem: [0..4096) sx buf0 (L0) / sh1 (L1); [4096..8192) sx buf1 (L0);
    //       [8192..12288) sh (both layers)
    __shared__ float smem[12288];
    float* const sxA = smem;
    float* const sxB = smem + 4096;
    float* const sh  = smem + 8192;
    float* const sh1 = smem;

    const float* WxL = Whx + (size_t)layer * H_ * E_;
    const float* WhL = Whh + (size_t)layer * H_ * H_;
    f32x4 wx0[4], wx1[4], wh0[4], wh1[4];
#pragma unroll
    for (int r = 0; r < 4; ++r) {
        const int row = rowbase + r;
        wx0[r] = *(const f32x4*)(WxL + (size_t)row * E_ + (lane << 2));
        wx1[r] = *(const f32x4*)(WxL + (size_t)row * E_ + 256 + (lane << 2));
        wh0[r] = *(const f32x4*)(WhL + (size_t)row * H_ + (lane << 2));
        wh1[r] = *(const f32x4*)(WhL + (size_t)row * H_ + 256 + (lane << 2));
    }
    const float bias = b_h[layer * H_ + rowbase + (lane & 3)];

    int sl4[4];
#pragma unroll
    for (int q = 0; q < 4; ++q) sl4[q] = seq_lens[eg0 + q];
    int Tg = 1;
#pragma unroll
    for (int j = 0; j < 8; ++j) {
        const int s = seq_lens[g * 8 + j];
        Tg = s > Tg ? s : Tg;
    }

    // L1 consume-flags: [8][32] x FPAD
    unsigned* const myflag = flags + ((size_t)(g * 32 + c)) * FPAD;
    const unsigned* const bp = flags + ((size_t)(g * 32 + (lane & 31))) * FPAD;

    const int se  = wid;                 // staging elem = wave id
    const int seg = g * 8 + se;

    long budget = 1l << 22;

    if (layer == 0) {
        // prologue: stage x(0)
        {
            const int tok = x[(size_t)seg * T_];
            *(f32x4*)&sxA[(se << 9) + (lane << 2)] =
                *(const f32x4*)(emb + ((size_t)tok << 9) + (lane << 2));
            *(f32x4*)&sxA[(se << 9) + 256 + (lane << 2)] =
                *(const f32x4*)(emb + ((size_t)tok << 9) + 256 + (lane << 2));
        }
        __syncthreads();

        for (int t = 0; t < Tg; ++t) {
            const int cur = t & 1, slot = t & 7, pslot = (t - 1) & 7;
            float* const sxc = cur ? sxB : sxA;
            float* const sxn = cur ? sxA : sxB;
            const unsigned em_prev = (((t - 1) >> 3) & 1) ? 0xFFFFFFFFu : 0u;
            const unsigned em_cur  = ((t >> 3) & 1) ? 0xFFFFFFFFu : 0u;

            // ---- backpressure (wave0, t>=RING): all L1 chunks consumed t-8 ----
            if (wid == 0 && t >= RING) {
                const int tgt = t - 7;
                for (;;) {
                    const unsigned v = flag_poll(bp);
                    const bool bad = (lane < 32) && ((int)v < tgt);
                    if (!__any(bad)) break;
                    if (--budget < 0) break;
                }
            }

            // ---- stage h0(t-1) with validity-retry; decode doubles as check ----
            if (t > 0) {
                const float* src = h0_ring + (((size_t)pslot << 6) + seg) * 512 + (lane << 2);
                f32x4 da, db;
                for (;;) {
                    f32x4 a, b;
                    coh_ld2k(src, a, b);
                    unsigned o = 0;
#pragma unroll
                    for (int m = 0; m < 4; ++m) {
                        unsigned u = __float_as_uint(a[m]) ^ em_prev; o |= u; da[m] = __uint_as_float(u);
                        unsigned w = __float_as_uint(b[m]) ^ em_prev; o |= w; db[m] = __uint_as_float(w);
                    }
                    if (!__any((o >> 30) & 1)) break;
                    if (--budget < 0) break;
                }
                *(f32x4*)&sh[(se << 9) + (lane << 2)] = da;
                *(f32x4*)&sh[(se << 9) + 256 + (lane << 2)] = db;
            } else {
                f32x4 z = 0;
                *(f32x4*)&sh[(se << 9) + (lane << 2)] = z;
                *(f32x4*)&sh[(se << 9) + 256 + (lane << 2)] = z;
            }
            // prefetch x(t+1)
            f32x4 px0, px1;
            const bool havepf = (t + 1 < Tg);
            if (havepf) {
                const int tok = x[(size_t)seg * T_ + t + 1];
                px0 = *(const f32x4*)(emb + ((size_t)tok << 9) + (lane << 2));
                px1 = *(const f32x4*)(emb + ((size_t)tok << 9) + 256 + (lane << 2));
            }
            __syncthreads();                       // barrier 1: sh ready

            // ---- compute + encoded store (always store: validity must progress) ----
#pragma unroll
            for (int q = 0; q < 4; ++q) {
                unsigned uenc = em_cur;            // encoded 0.0 for finished elems
                if (t < sl4[q]) {
                    const int el = (we << 2) + q;
                    const f32x4 lx0 = *(const f32x4*)&sxc[(el << 9) + (lane << 2)];
                    const f32x4 lx1 = *(const f32x4*)&sxc[(el << 9) + 256 + (lane << 2)];
                    const f32x4 h0a = *(const f32x4*)&sh[(el << 9) + (lane << 2)];
                    const f32x4 h0b = *(const f32x4*)&sh[(el << 9) + 256 + (lane << 2)];
                    float vv[4];
#pragma unroll
                    for (int r = 0; r < 4; ++r) {
                        float s = wx0[r][0] * lx0[0];
                        s = fmaf(wx0[r][1], lx0[1], s);
                        s = fmaf(wx0[r][2], lx0[2], s);
                        s = fmaf(wx0[r][3], lx0[3], s);
                        s = fmaf(wx1[r][0], lx1[0], s);
                        s = fmaf(wx1[r][1], lx1[1], s);
                        s = fmaf(wx1[r][2], lx1[2], s);
                        s = fmaf(wx1[r][3], lx1[3], s);
                        s = fmaf(wh0[r][0], h0a[0], s);
                        s = fmaf(wh0[r][1], h0a[1], s);
                        s = fmaf(wh0[r][2], h0a[2], s);
                        s = fmaf(wh0[r][3], h0a[3], s);
                        s = fmaf(wh1[r][0], h0b[0], s);
                        s = fmaf(wh1[r][1], h0b[1], s);
                        s = fmaf(wh1[r][2], h0b[2], s);
                        s = fmaf(wh1[r][3], h0b[3], s);
                        vv[r] = s;
                    }
                    const float sum = reduce4(vv, lane);
                    const float hv = fast_tanh(sum + bias);
                    uenc = __float_as_uint(hv) ^ em_cur;
                }
                if (lane < 4)
                    coh_store_u(h0_ring + (((size_t)slot << 6) + eg0 + q) * 512 + rowbase + lane, uenc);
            }
            if (havepf) {
                *(f32x4*)&sxn[(se << 9) + (lane << 2)] = px0;
                *(f32x4*)&sxn[(se << 9) + 256 + (lane << 2)] = px1;
            }
            __syncthreads();                       // barrier 2
        }
    } else {
        // ---- layer 1 ----
        for (int t = 0; t < Tg; ++t) {
            const int slot = t & 7, pslot = (t - 1) & 7;
            const unsigned em0 = ((t >> 3) & 1) ? 0xFFFFFFFFu : 0u;          // h0(t)
            const unsigned em1 = (((t - 1) >> 3) & 1) ? 0xFFFFFFFFu : 0u;    // h1(t-1)

            // ---- stage h0(t) -> sh and h1(t-1) -> sh1, validity-retry ----
            const float* p0 = h0_ring + (((size_t)slot << 6) + seg) * 512 + (lane << 2);
            if (t > 0) {
                const float* p1 = h1_ring + (((size_t)pslot << 6) + seg) * 512 + (lane << 2);
                f32x4 d0a, d0b, d1a, d1b;
                for (;;) {
                    f32x4 a, b, c2, d2;
                    coh_ld4k(p0, p1, a, b, c2, d2);
                    unsigned o = 0;
#pragma unroll
                    for (int m = 0; m < 4; ++m) {
                        unsigned u0 = __float_as_uint(a[m])  ^ em0; o |= u0; d0a[m] = __uint_as_float(u0);
                        unsigned u1 = __float_as_uint(b[m])  ^ em0; o |= u1; d0b[m] = __uint_as_float(u1);
                        unsigned u2 = __float_as_uint(c2[m]) ^ em1; o |= u2; d1a[m] = __uint_as_float(u2);
                        unsigned u3 = __float_as_uint(d2[m]) ^ em1; o |= u3; d1b[m] = __uint_as_float(u3);
                    }
                    if (!__any((o >> 30) & 1)) break;
                    if (--budget < 0) break;
                }
                *(f32x4*)&sh[(se << 9) + (lane << 2)] = d0a;
                *(f32x4*)&sh[(se << 9) + 256 + (lane << 2)] = d0b;
                *(f32x4*)&sh1[(se << 9) + (lane << 2)] = d1a;
                *(f32x4*)&sh1[(se << 9) + 256 + (lane << 2)] = d1b;
            } else {
                f32x4 d0a, d0b;
                for (;;) {
                    f32x4 a, b;
                    coh_ld2k(p0, a, b);
                    unsigned o = 0;
#pragma unroll
                    for (int m = 0; m < 4; ++m) {
                        unsigned u0 = __float_as_uint(a[m]) ^ em0; o |= u0; d0a[m] = __uint_as_float(u0);
                        unsigned u1 = __float_as_uint(b[m]) ^ em0; o |= u1; d0b[m] = __uint_as_float(u1);
                    }
                    if (!__any((o >> 30) & 1)) break;
                    if (--budget < 0) break;
                }
                *(f32x4*)&sh[(se << 9) + (lane << 2)] = d0a;
                *(f32x4*)&sh[(se << 9) + 256 + (lane << 2)] = d0b;
                f32x4 z = 0;
                *(f32x4*)&sh1[(se << 9) + (lane << 2)] = z;
                *(f32x4*)&sh1[(se << 9) + 256 + (lane << 2)] = z;
            }
            __syncthreads();                       // barrier 1: staged
            if (tid == 0) flag_store(myflag, (unsigned)(t + 1));   // consumed t (backpressure)

#pragma unroll
            for (int q = 0; q < 4; ++q) {
                unsigned uenc = em0;               // encoded 0.0 for finished elems
                const bool live = (t < sl4[q]);
                float hv = 0.f;
                if (live) {
                    const int el = (we << 2) + q;
                    const f32x4 xa = *(const f32x4*)&sh[(el << 9) + (lane << 2)];
                    const f32x4 xb = *(const f32x4*)&sh[(el << 9) + 256 + (lane << 2)];
                    const f32x4 ha = *(const f32x4*)&sh1[(el << 9) + (lane << 2)];
                    const f32x4 hb = *(const f32x4*)&sh1[(el << 9) + 256 + (lane << 2)];
                    float vv[4];
#pragma unroll
                    for (int r = 0; r < 4; ++r) {
                        float s = wx0[r][0] * xa[0];
                        s = fmaf(wx0[r][1], xa[1], s);
                        s = fmaf(wx0[r][2], xa[2], s);
                        s = fmaf(wx0[r][3], xa[3], s);
                        s = fmaf(wx1[r][0], xb[0], s);
                        s = fmaf(wx1[r][1], xb[1], s);
                        s = fmaf(wx1[r][2], xb[2], s);
                        s = fmaf(wx1[r][3], xb[3], s);
                        s = fmaf(wh0[r][0], ha[0], s);
                        s = fmaf(wh0[r][1], ha[1], s);
                        s = fmaf(wh0[r][2], ha[2], s);
                        s = fmaf(wh0[r][3], ha[3], s);
                        s = fmaf(wh1[r][0], hb[0], s);
                        s = fmaf(wh1[r][1], hb[1], s);
                        s = fmaf(wh1[r][2], hb[2], s);
                        s = fmaf(wh1[r][3], hb[3], s);
                        vv[r] = s;
                    }
                    const float sum = reduce4(vv, lane);
                    hv = fast_tanh(sum + bias);
                    uenc = __float_as_uint(hv) ^ em0;
                }
                if (lane < 4) {
                    coh_store_u(h1_ring + (((size_t)slot << 6) + eg0 + q) * 512 + rowbase + lane, uenc);
                    if (live && t == sl4[q] - 1)
                        h1_final[((size_t)(eg0 + q) << 9) + rowbase + lane] = hv;
                }
            }
            __syncthreads();                       // barrier 2
        }
    }
}

// ---- final head: y = Wyh[1] @ h1 + b_y[1]; out = Wf @ y + bf ----
__device__ __forceinline__ float dot4(float4 a, float4 b) {
    return fmaf(a.x, b.x, fmaf(a.y, b.y, fmaf(a.z, b.z, a.w * b.w)));
}
__device__ __forceinline__ float wave_reduce(float acc) {
#pragma unroll
    for (int off = 32; off > 0; off >>= 1) acc += __shfl_down(acc, off, 64);
    return acc;
}

__global__ __launch_bounds__(512) void head_kernel(
    const float* __restrict__ h1f, const float* __restrict__ Wyh,
    const float* __restrict__ b_y, const float* __restrict__ Wf,
    const float* __restrict__ bf, float* __restrict__ out)
{
    const int e = blockIdx.x;
    const int tid = threadIdx.x, wid = tid >> 6, lane = tid & 63;
    const int k0 = lane << 3;
    __shared__ float sh[H_];
    __shared__ float sy[H_];
    sh[tid] = h1f[(size_t)e * H_ + tid];
    __syncthreads();
    const float4 hA = *(const float4*)&sh[k0];
    const float4 hB = *(const float4*)&sh[k0 + 4];
    const float* Wy1 = Wyh + H_ * H_;
#pragma unroll 4
    for (int rr = 0; rr < 64; ++rr) {
        const int row = (wid << 6) + rr;
        float acc = wave_reduce(dot4(*(const float4*)&Wy1[(size_t)row * H_ + k0], hA) +
                                dot4(*(const float4*)&Wy1[(size_t)row * H_ + k0 + 4], hB));
        if (lane == 0) sy[row] = acc + b_y[H_ + row];
    }
    __syncthreads();
    const float4 yA = *(const float4*)&sy[k0];
    const float4 yB = *(const float4*)&sy[k0 + 4];
#pragma unroll
    for (int rr = 0; rr < 4; ++rr) {
        const int o = (wid << 2) + rr;
        float acc = wave_reduce(dot4(*(const float4*)&Wf[(size_t)o * H_ + k0], yA) +
                                dot4(*(const float4*)&Wf[(size_t)o * H_ + k0 + 4], yB));
        if (lane == 0) out[(size_t)e * O_ + o] = acc + bf[o];
    }
}

// ---- fallback (round-0, known-passing) ----
__global__ __launch_bounds__(1024, 1) void rnn_fused_fb(
    const int* __restrict__ x, const int* __restrict__ seq_lens,
    const float* __restrict__ emb, const float* __restrict__ Whx,
    const float* __restrict__ Whh, const float* __restrict__ b_h,
    const float* __restrict__ Wyh, const float* __restrict__ b_y,
    const float* __restrict__ Wf, const float* __restrict__ bf,
    float* __restrict__ out)
{
    const int b = blockIdx.x, tid = threadIdx.x;
    const int wave = tid >> 6, lane = tid & 63, k0 = lane << 3;
    __shared__ float s_inp[E_];
    __shared__ float s_h0[2][H_];
    __shared__ float s_h1[2][H_];
    __shared__ float s_y[H_];
    if (tid < H_) { s_h0[0][tid]=0.f; s_h0[1][tid]=0.f; s_h1[0][tid]=0.f; s_h1[1][tid]=0.f; }
    const int Tb = seq_lens[b];
    const float* Whx0 = Whx; const float* Whx1 = Whx + H_*E_;
    const float* Whh0 = Whh; const float* Whh1 = Whh + H_*H_;
    for (int t = 0; t < Tb; ++t) {
        const int cur = t & 1, prv = cur ^ 1;
        if (tid < E_) { const int tok = x[b*T_+t]; s_inp[tid] = emb[(size_t)tok*E_+tid]; }
        __syncthreads();
        const float4 iA = *(const float4*)&s_inp[k0], iB = *(const float4*)&s_inp[k0+4];
        const float4 pA = *(const float4*)&s_h0[prv][k0], pB = *(const float4*)&s_h0[prv][k0+4];
#pragma unroll 4
        for (int r = 0; r < 32; ++r) {
            const int i = (wave<<5)+r;
            float acc = dot4(*(const float4*)&Whx0[i*E_+k0], iA) + dot4(*(const float4*)&Whx0[i*E_+k0+4], iB)
                      + dot4(*(const float4*)&Whh0[i*H_+k0], pA) + dot4(*(const float4*)&Whh0[i*H_+k0+4], pB);
            acc = wave_reduce(acc);
            if (lane == 0) s_h0[cur][i] = tanhf(acc + b_h[i]);
        }
        __syncthreads();
        const float4 cA = *(const float4*)&s_h0[cur][k0], cB = *(const float4*)&s_h0[cur][k0+4];
        const float4 qA = *(const float4*)&s_h1[prv][k0], qB = *(const float4*)&s_h1[prv][k0+4];
#pragma unroll 4
        for (int r = 0; r < 32; ++r) {
            const int i = (wave<<5)+r;
            float acc = dot4(*(const float4*)&Whx1[i*E_+k0], cA) + dot4(*(const float4*)&Whx1[i*E_+k0+4], cB)
                      + dot4(*(const float4*)&Whh1[i*H_+k0], qA) + dot4(*(const float4*)&Whh1[i*H_+k0+4], qB);
            acc = wave_reduce(acc);
            if (lane == 0) s_h1[cur][i] = tanhf(acc + b_h[H_+i]);
        }
        __syncthreads();
    }
    const int lastb = (Tb-1) & 1;
    const float4 hA = *(const float4*)&s_h1[lastb][k0], hB = *(const float4*)&s_h1[lastb][k0+4];
    const float* Wy1 = Wyh + H_*H_;
#pragma unroll 4
    for (int r = 0; r < 32; ++r) {
        const int i = (wave<<5)+r;
        float acc = wave_reduce(dot4(*(const float4*)&Wy1[i*H_+k0], hA) + dot4(*(const float4*)&Wy1[i*H_+k0+4], hB));
        if (lane == 0) s_y[i] = acc + b_y[H_+i];
    }
    __syncthreads();
    const float4 yA = *(const float4*)&s_y[k0], yB = *(const float4*)&s_y[k0+4];
    if (wave < 8) {
#pragma unroll
        for (int r = 0; r < 4; ++r) {
            const int o = (wave<<2)+r;
            float acc = wave_reduce(dot4(*(const float4*)&Wf[o*H_+k0], yA) + dot4(*(const float4*)&Wf[o*H_+k0+4], yB));
            if (lane == 0) out[b*O_+o] = acc + bf[o];
        }
    }
}

extern "C" void kernel_launch(void* const* d_in, const int* in_sizes, int n_in,
                              void* d_out, int out_size, void* d_ws, size_t ws_size,
                              hipStream_t stream) {
    const int*   x    = (const int*)d_in[0];
    const int*   sl   = (const int*)d_in[1];
    const float* emb  = (const float*)d_in[2];
    const float* Whx  = (const float*)d_in[3];
    const float* Whh  = (const float*)d_in[4];
    const float* b_h  = (const float*)d_in[5];
    const float* Wyh  = (const float*)d_in[6];
    const float* b_y  = (const float*)d_in[7];
    const float* Wf   = (const float*)d_in[8];
    const float* bf   = (const float*)d_in[9];
    float* out = (float*)d_out;

    if (ws_size < WS_REQUIRED) {
        rnn_fused_fb<<<B_, 1024, 0, stream>>>(x, sl, emb, Whx, Whh, b_h, Wyh, b_y, Wf, bf, out);
        return;
    }

    float* ws_f = (float*)d_ws;
    float* h0_ring = ws_f + H0_OFF;
    float* h1_ring = ws_f + H1_OFF;
    float* h1f     = ws_f + HF_OFF;
    unsigned* flags = (unsigned*)(ws_f + FLAG_OFF);

    // rings poisoned to 0xFF (exponent 255 -> stale for epoch 0); flags zeroed
    hipMemsetAsync(h0_ring, 0xFF, 2 * H1_OFF * sizeof(float), stream);
    hipMemsetAsync(flags, 0, FLAG_UINTS * sizeof(unsigned), stream);
    rnn_pipe11<<<512, 512, 0, stream>>>(x, sl, emb, Whx, Whh, b_h,
                                        h0_ring, h1_ring, h1f, flags);
    head_kernel<<<B_, 512, 0, stream>>>(h1f, Wyh, b_y, Wf, bf, out);
}